// Round 1
// baseline (806.667 us; speedup 1.0000x reference)
//
#include <hip/hip_runtime.h>

#define THRE 4.0f

__device__ __forceinline__ float spikef(float x) {
    return floorf(fminf(fmaxf(x, 0.0f), THRE) + 0.5f);
}

// ---------- elementwise spike ----------
__global__ void k_spike(const float* __restrict__ x, float* __restrict__ y, int n) {
    int i = blockIdx.x * 256 + threadIdx.x;
    if (i < n) y[i] = spikef(x[i]);
}

// ---------- fp32 GEMM: C[M,N] = A[M,K] @ B[N,K]^T (+bias) ----------
// 64x64 tile, 256 threads, 4x4 micro-tile, K-step 16. M,N,K all divisible.
template<bool BIAS>
__global__ __launch_bounds__(256) void k_gemm(const float* __restrict__ A,
                                              const float* __restrict__ B,
                                              const float* __restrict__ bias,
                                              float* __restrict__ C,
                                              int M, int N, int K) {
    __shared__ float As[16][68];
    __shared__ float Bs[16][68];
    const int tid = threadIdx.x;
    const int tx = tid & 15;   // n micro
    const int ty = tid >> 4;   // m micro
    const int n0 = blockIdx.x * 64;
    const int m0 = blockIdx.y * 64;
    const int lc = tid & 15;   // k within tile
    const int lr = tid >> 4;   // row within tile (x4)
    float acc[4][4] = {};
    for (int k0 = 0; k0 < K; k0 += 16) {
        #pragma unroll
        for (int q = 0; q < 4; ++q) {
            As[lc][lr + 16*q] = A[(size_t)(m0 + lr + 16*q) * K + k0 + lc];
            Bs[lc][lr + 16*q] = B[(size_t)(n0 + lr + 16*q) * K + k0 + lc];
        }
        __syncthreads();
        #pragma unroll
        for (int kk = 0; kk < 16; ++kk) {
            float a[4], b[4];
            #pragma unroll
            for (int i = 0; i < 4; ++i) a[i] = As[kk][ty*4 + i];
            #pragma unroll
            for (int j = 0; j < 4; ++j) b[j] = Bs[kk][tx*4 + j];
            #pragma unroll
            for (int i = 0; i < 4; ++i)
                #pragma unroll
                for (int j = 0; j < 4; ++j)
                    acc[i][j] = fmaf(a[i], b[j], acc[i][j]);
        }
        __syncthreads();
    }
    #pragma unroll
    for (int i = 0; i < 4; ++i) {
        const int m = m0 + ty*4 + i;
        #pragma unroll
        for (int j = 0; j < 4; ++j) {
            const int n = n0 + tx*4 + j;
            float v = acc[i][j];
            if (BIAS) v += bias[n];
            C[(size_t)m * N + n] = v;
        }
    }
}

// ---------- BatchNorm stats (two-stage, deterministic) ----------
// Stage 1: grid (6, 16): 256 channels per x-block, 256 rows per y-block.
__global__ void k_bn_partial(const float* __restrict__ qkv,
                             float* __restrict__ psum, float* __restrict__ psq) {
    const int c = blockIdx.x * 256 + threadIdx.x;   // 0..1535
    const int r0 = blockIdx.y * 256;
    float s = 0.f, q = 0.f;
    for (int r = r0; r < r0 + 256; ++r) {
        float v = qkv[(size_t)r * 1536 + c];
        s += v;
        q = fmaf(v, v, q);
    }
    psum[blockIdx.y * 1536 + c] = s;
    psq [blockIdx.y * 1536 + c] = q;
}

__global__ void k_bn_finalize(const float* __restrict__ psum, const float* __restrict__ psq,
                              float* __restrict__ mean, float* __restrict__ invstd) {
    const int c = blockIdx.x * 256 + threadIdx.x;   // 6 blocks -> 1536
    double s = 0.0, q = 0.0;
    for (int b = 0; b < 16; ++b) { s += (double)psum[b*1536 + c]; q += (double)psq[b*1536 + c]; }
    const double mu  = s / 4096.0;
    const double var = q / 4096.0 - mu * mu;
    mean[c]   = (float)mu;
    invstd[c] = (float)(1.0 / sqrt(var + 1e-5));
}

// ---------- normalize + spike (in place) ----------
__global__ void k_bn_spike(float* __restrict__ qkv,
                           const float* __restrict__ mean,
                           const float* __restrict__ invstd,
                           const float* __restrict__ gamma,
                           const float* __restrict__ beta) {
    const size_t off = (size_t)blockIdx.x * 1536;   // one row per block, 4096 rows
    for (int c = threadIdx.x; c < 1536; c += 256) {
        float v = (qkv[off + c] - mean[c]) * invstd[c] * gamma[c] + beta[c];
        qkv[off + c] = spikef(v);
    }
}

// ---------- fused attention (no softmax): sout = spike(scale * spike(qk^T) v) ----------
// grid (16 ntiles, 8 heads, 4 batch); block 256. q/k/v read from spiked qkv
// layout [B,N,3C] with channel d = s*512 + h*64 + e. Output in [B,N,C] layout.
__global__ __launch_bounds__(256) void k_attn(const float* __restrict__ sqkv,
                                              float* __restrict__ sout) {
    __shared__ float qs[64][64];   // q tile, broadcast reads
    __shared__ float ks[64][68];   // k tile (row-major), reused to hold S
    __shared__ float vt[64][68];   // v^T tile: vt[e][j]
    const int tid = threadIdx.x;
    const int tx = tid & 63;
    const int ty = tid >> 6;
    const int b = blockIdx.z, h = blockIdx.y;
    const int n0 = blockIdx.x * 64;
    const float scale = 0.125f;   // hd^-0.5, hd=64
    const float* base = sqkv + (size_t)b * 1024 * 1536 + h * 64;

    for (int i = ty; i < 64; i += 4)
        qs[i][tx] = base[(size_t)(n0 + i) * 1536 + tx];

    float acc[16];
    #pragma unroll
    for (int ii = 0; ii < 16; ++ii) acc[ii] = 0.f;

    for (int m0 = 0; m0 < 1024; m0 += 64) {
        __syncthreads();   // previous-iter reads done; also orders qs writes
        for (int j = ty; j < 64; j += 4) {
            ks[j][tx] = base[(size_t)(m0 + j) * 1536 +  512 + tx];
            vt[tx][j] = base[(size_t)(m0 + j) * 1536 + 1024 + tx];
        }
        __syncthreads();
        // my k row (j = tx) into registers
        float kreg[64];
        #pragma unroll
        for (int e = 0; e < 64; e += 4) {
            float4 t = *(const float4*)&ks[tx][e];
            kreg[e] = t.x; kreg[e+1] = t.y; kreg[e+2] = t.z; kreg[e+3] = t.w;
        }
        // S[i][tx] for my 16 rows
        float sreg[16];
        #pragma unroll
        for (int ii = 0; ii < 16; ++ii) {
            const int i = ty + 4*ii;
            float s = 0.f;
            #pragma unroll
            for (int e = 0; e < 64; ++e) s = fmaf(qs[i][e], kreg[e], s);
            sreg[ii] = spikef(s);
        }
        __syncthreads();   // everyone done reading ks as k
        #pragma unroll
        for (int ii = 0; ii < 16; ++ii) ks[ty + 4*ii][tx] = sreg[ii];   // S into ks
        __syncthreads();
        // my v column (e = tx) into registers
        float vreg[64];
        #pragma unroll
        for (int j = 0; j < 64; j += 4) {
            float4 t = *(const float4*)&vt[tx][j];
            vreg[j] = t.x; vreg[j+1] = t.y; vreg[j+2] = t.z; vreg[j+3] = t.w;
        }
        #pragma unroll
        for (int ii = 0; ii < 16; ++ii) {
            const int i = ty + 4*ii;
            float s = acc[ii];
            #pragma unroll
            for (int j = 0; j < 64; ++j) s = fmaf(ks[i][j], vreg[j], s);
            acc[ii] = s;
        }
    }
    float* obase = sout + (size_t)b * 1024 * 512 + h * 64;
    #pragma unroll
    for (int ii = 0; ii < 16; ++ii) {
        const int i = ty + 4*ii;
        obase[(size_t)(n0 + i) * 512 + tx] = spikef(acc[ii] * scale);
    }
}

extern "C" void kernel_launch(void* const* d_in, const int* in_sizes, int n_in,
                              void* d_out, int out_size, void* d_ws, size_t ws_size,
                              hipStream_t stream) {
    const float* x     = (const float*)d_in[0];
    const float* Wqkv  = (const float*)d_in[1];
    const float* gamma = (const float*)d_in[2];
    const float* beta  = (const float*)d_in[3];
    const float* Wproj = (const float*)d_in[4];
    const float* bproj = (const float*)d_in[5];
    float* out = (float*)d_out;

    // workspace layout (floats): xs/sout 2,097,152 | qkv 6,291,456 | bn partials+stats
    float* w    = (float*)d_ws;
    float* xs   = w;                           // reused as sout after qkv GEMM
    float* qkv  = w + 2097152;
    float* psum = w + 2097152 + 6291456;
    float* psq  = psum + 16*1536;
    float* mean = psq  + 16*1536;
    float* istd = mean + 1536;

    k_spike<<<8192, 256, 0, stream>>>(x, xs, 4096*512);
    k_gemm<false><<<dim3(24, 64), 256, 0, stream>>>(xs, Wqkv, nullptr, qkv, 4096, 1536, 512);
    k_bn_partial<<<dim3(6, 16), 256, 0, stream>>>(qkv, psum, psq);
    k_bn_finalize<<<6, 256, 0, stream>>>(psum, psq, mean, istd);
    k_bn_spike<<<4096, 256, 0, stream>>>(qkv, mean, istd, gamma, beta);
    k_attn<<<dim3(16, 8, 4), 256, 0, stream>>>(qkv, xs);
    k_gemm<true><<<dim3(8, 64), 256, 0, stream>>>(xs, Wproj, bproj, out, 4096, 512, 512);
}

// Round 2
// 195.589 us; speedup vs baseline: 4.1243x; 4.1243x over previous
//
#include <hip/hip_runtime.h>

typedef __attribute__((ext_vector_type(8))) short short8;
typedef __attribute__((ext_vector_type(4))) float f32x4;

#define THRE 4.0f

__device__ __forceinline__ float spikef(float x) {
    return floorf(fminf(fmaxf(x, 0.0f), THRE) + 0.5f);
}
__device__ __forceinline__ short f2bf(float f) {   // truncate; exact for small ints
    return (short)(__builtin_bit_cast(unsigned int, f) >> 16);
}

// ---------- split fp32 weights into bf16 hi|lo, layout [N][2K] ----------
__global__ void k_splitw(const float* __restrict__ W, short* __restrict__ Wd, int n, int K) {
    int i = blockIdx.x * 256 + threadIdx.x;
    if (i >= n) return;
    int r = i / K, c = i % K;
    float f = W[i];
    unsigned u = __builtin_bit_cast(unsigned int, f);
    short hi = (short)(u >> 16);
    float fhi = __builtin_bit_cast(float, u & 0xffff0000u);
    float lo = f - fhi;                       // exact (Sterbenz)
    Wd[(size_t)r * 2 * K + c]     = hi;
    Wd[(size_t)r * 2 * K + K + c] = f2bf(lo);
}

// ---------- spike(x) -> bf16, duplicated halves [4096][1024] ----------
__global__ void k_spike_dup(const float* __restrict__ x, short* __restrict__ xs2) {
    int i = blockIdx.x * 256 + threadIdx.x;   // 4096*512
    int r = i >> 9, c = i & 511;
    short b = f2bf(spikef(x[i]));
    xs2[(size_t)r * 1024 + c]       = b;
    xs2[(size_t)r * 1024 + 512 + c] = b;
}

// ---------- bf16 MFMA GEMM: C[M,N] = A[M,K] @ B[N,K]^T (+bias), fp32 out ----------
// BM=BN=128, BK=32, 256 threads (2x2 waves, each 64x64 via 4x4 of 16x16x32).
template<bool BIAS>
__global__ __launch_bounds__(256) void k_gemm_bf16(const short* __restrict__ A,
                                                   const short* __restrict__ B,
                                                   const float* __restrict__ bias,
                                                   float* __restrict__ C,
                                                   int M, int N, int K) {
    __shared__ short As[128 * 40];   // rows padded 32->40 shorts (80B, odd multiple of 16B)
    __shared__ short Bs[128 * 40];
    const int tid  = threadIdx.x;
    const int lane = tid & 63, wave = tid >> 6;
    const int wy = wave >> 1, wx = wave & 1;
    const int quad = lane >> 4, l16 = lane & 15;
    const int m0 = blockIdx.y * 128, n0 = blockIdx.x * 128;

    f32x4 acc[4][4];
    #pragma unroll
    for (int i = 0; i < 4; ++i)
        #pragma unroll
        for (int j = 0; j < 4; ++j)
            #pragma unroll
            for (int r = 0; r < 4; ++r) acc[i][j][r] = 0.f;

    const int srow = tid >> 1;            // staging: 2 threads/row, 32B each
    const int sc0  = (tid & 1) * 2;       // chunk base (8-short chunks)
    const short* Ag = A + (size_t)(m0 + srow) * K + sc0 * 8;
    const short* Bg = B + (size_t)(n0 + srow) * K + sc0 * 8;
    short* AsW = &As[srow * 40 + sc0 * 8];
    short* BsW = &Bs[srow * 40 + sc0 * 8];

    for (int k0 = 0; k0 < K; k0 += 32) {
        __syncthreads();
        short8 a0 = *(const short8*)(Ag + k0);
        short8 a1 = *(const short8*)(Ag + k0 + 8);
        short8 b0 = *(const short8*)(Bg + k0);
        short8 b1 = *(const short8*)(Bg + k0 + 8);
        *(short8*)(AsW)     = a0;
        *(short8*)(AsW + 8) = a1;
        *(short8*)(BsW)     = b0;
        *(short8*)(BsW + 8) = b1;
        __syncthreads();
        short8 aF[4], bF[4];
        #pragma unroll
        for (int mt = 0; mt < 4; ++mt)
            aF[mt] = *(const short8*)&As[(wy * 64 + mt * 16 + l16) * 40 + quad * 8];
        #pragma unroll
        for (int nt = 0; nt < 4; ++nt)
            bF[nt] = *(const short8*)&Bs[(wx * 64 + nt * 16 + l16) * 40 + quad * 8];
        #pragma unroll
        for (int mt = 0; mt < 4; ++mt)
            #pragma unroll
            for (int nt = 0; nt < 4; ++nt)
                acc[mt][nt] = __builtin_amdgcn_mfma_f32_16x16x32_bf16(aF[mt], bF[nt], acc[mt][nt], 0, 0, 0);
    }

    float bs[4];
    #pragma unroll
    for (int nt = 0; nt < 4; ++nt) bs[nt] = BIAS ? bias[n0 + wx * 64 + nt * 16 + l16] : 0.f;
    #pragma unroll
    for (int mt = 0; mt < 4; ++mt)
        #pragma unroll
        for (int r = 0; r < 4; ++r) {
            int row = m0 + wy * 64 + mt * 16 + quad * 4 + r;
            float* Cr = C + (size_t)row * N + n0 + wx * 64 + l16;
            #pragma unroll
            for (int nt = 0; nt < 4; ++nt) Cr[nt * 16] = acc[mt][nt][r] + bs[nt];
        }
}

// ---------- BatchNorm stats (two-stage, deterministic) ----------
__global__ void k_bn_partial(const float* __restrict__ qkv,
                             float* __restrict__ psum, float* __restrict__ psq) {
    const int c = blockIdx.x * 256 + threadIdx.x;   // 0..1535
    const int r0 = blockIdx.y * 64;
    float s = 0.f, q = 0.f;
    for (int r = r0; r < r0 + 64; ++r) {
        float v = qkv[(size_t)r * 1536 + c];
        s += v;
        q = fmaf(v, v, q);
    }
    psum[blockIdx.y * 1536 + c] = s;
    psq [blockIdx.y * 1536 + c] = q;
}

__global__ void k_bn_finalize(const float* __restrict__ psum, const float* __restrict__ psq,
                              float* __restrict__ mean, float* __restrict__ invstd) {
    const int c = blockIdx.x * 256 + threadIdx.x;
    double s = 0.0, q = 0.0;
    for (int b = 0; b < 64; ++b) { s += (double)psum[b * 1536 + c]; q += (double)psq[b * 1536 + c]; }
    const double mu  = s / 4096.0;
    const double var = q / 4096.0 - mu * mu;
    mean[c]   = (float)mu;
    invstd[c] = (float)(1.0 / sqrt(var + 1e-5));
}

// ---------- BN + spike -> packed bf16 q/k (per-head rows) and v (transposed) ----------
// qp,kp: [B,H,1024,64]; vt: [B,H,64,1024]
__global__ void k_bn_spike(const float* __restrict__ qkv,
                           const float* __restrict__ mean, const float* __restrict__ invstd,
                           const float* __restrict__ gamma, const float* __restrict__ beta,
                           short* __restrict__ qp, short* __restrict__ kp, short* __restrict__ vt) {
    const int row = blockIdx.x;              // 0..4095
    const int b = row >> 10, n = row & 1023;
    const size_t off = (size_t)row * 1536;
    for (int c = threadIdx.x; c < 1536; c += 256) {
        float v = (qkv[off + c] - mean[c]) * invstd[c] * gamma[c] + beta[c];
        short s = f2bf(spikef(v));
        if (c < 512) {
            qp[(((size_t)b * 8 + (c >> 6)) * 1024 + n) * 64 + (c & 63)] = s;
        } else if (c < 1024) {
            int c2 = c - 512;
            kp[(((size_t)b * 8 + (c2 >> 6)) * 1024 + n) * 64 + (c2 & 63)] = s;
        } else {
            int c2 = c - 1024;
            vt[(((size_t)b * 8 + (c2 >> 6)) * 64 + (c2 & 63)) * 1024 + n] = s;
        }
    }
}

// ---------- fused MFMA attention: sout = spike(0.125 * spike(q k^T) v) ----------
// grid (16, 8, 4): 64 q-rows per block, kv tiled by 128. 256 threads = 4 waves.
// All values {0..4}: bit-exact in bf16 MFMA with fp32 accumulate.
__global__ __launch_bounds__(256) void k_attn(const short* __restrict__ qp,
                                              const short* __restrict__ kp,
                                              const short* __restrict__ vt,
                                              short* __restrict__ sout) {
    __shared__ short Qs[64 * 72];    // [qrow][e], pad 64->72
    __shared__ short Ks[128 * 72];   // [kvrow][e], pad
    __shared__ short Vs[64 * 136];   // [e][kvrow], pad 128->136
    __shared__ short Sb[64 * 136];   // spiked S, [qrow][kvrow], pad
    const int tid  = threadIdx.x;
    const int lane = tid & 63, w = tid >> 6;
    const int quad = lane >> 4, l16 = lane & 15;
    const int b = blockIdx.z, h = blockIdx.y;
    const int n0 = blockIdx.x * 64;
    const size_t bh = (size_t)b * 8 + h;

    // stage Q (64x64) once
    {
        const int row = tid >> 2, c0 = (tid & 3) * 2;     // 2 chunks of 8 shorts
        const short* g = qp + (bh * 1024 + n0 + row) * 64 + c0 * 8;
        *(short8*)&Qs[row * 72 + c0 * 8]     = *(const short8*)(g);
        *(short8*)&Qs[row * 72 + c0 * 8 + 8] = *(const short8*)(g + 8);
    }
    __syncthreads();
    short8 qf[4][2];
    #pragma unroll
    for (int mt = 0; mt < 4; ++mt)
        #pragma unroll
        for (int kq = 0; kq < 2; ++kq)
            qf[mt][kq] = *(const short8*)&Qs[(mt * 16 + l16) * 72 + kq * 32 + quad * 8];

    f32x4 of[4];
    #pragma unroll
    for (int mt = 0; mt < 4; ++mt)
        #pragma unroll
        for (int r = 0; r < 4; ++r) of[mt][r] = 0.f;

    // staging index helpers
    const int krow = tid >> 1, kc0 = (tid & 1) * 4;       // K: 4 chunks/thread
    const int ve = tid >> 2,  vc0 = (tid & 3) * 4;        // V: 4 chunks/thread

    for (int j0 = 0; j0 < 1024; j0 += 128) {
        __syncthreads();   // prior PV reads of Vs/Sb done before restage
        {
            const short* g = kp + (bh * 1024 + j0 + krow) * 64 + kc0 * 8;
            #pragma unroll
            for (int i = 0; i < 4; ++i)
                *(short8*)&Ks[krow * 72 + (kc0 + i) * 8] = *(const short8*)(g + i * 8);
            const short* gv = vt + (bh * 64 + ve) * 1024 + j0 + vc0 * 8;
            #pragma unroll
            for (int i = 0; i < 4; ++i)
                *(short8*)&Vs[ve * 136 + (vc0 + i) * 8] = *(const short8*)(gv + i * 8);
        }
        __syncthreads();

        // S = Q @ K^T : wave w computes S[0:64][w*32 : w*32+32]
        f32x4 sacc[4][2];
        #pragma unroll
        for (int mt = 0; mt < 4; ++mt)
            #pragma unroll
            for (int nt = 0; nt < 2; ++nt)
                #pragma unroll
                for (int r = 0; r < 4; ++r) sacc[mt][nt][r] = 0.f;
        #pragma unroll
        for (int kq = 0; kq < 2; ++kq) {
            short8 kf0 = *(const short8*)&Ks[(w * 32 +      l16) * 72 + kq * 32 + quad * 8];
            short8 kf1 = *(const short8*)&Ks[(w * 32 + 16 + l16) * 72 + kq * 32 + quad * 8];
            #pragma unroll
            for (int mt = 0; mt < 4; ++mt) {
                sacc[mt][0] = __builtin_amdgcn_mfma_f32_16x16x32_bf16(qf[mt][kq], kf0, sacc[mt][0], 0, 0, 0);
                sacc[mt][1] = __builtin_amdgcn_mfma_f32_16x16x32_bf16(qf[mt][kq], kf1, sacc[mt][1], 0, 0, 0);
            }
        }
        // spike(S) -> Sb in [m][j] (A-operand friendly)
        #pragma unroll
        for (int mt = 0; mt < 4; ++mt)
            #pragma unroll
            for (int nt = 0; nt < 2; ++nt)
                #pragma unroll
                for (int r = 0; r < 4; ++r)
                    Sb[(mt * 16 + quad * 4 + r) * 136 + w * 32 + nt * 16 + l16] =
                        f2bf(spikef(sacc[mt][nt][r]));
        __syncthreads();

        // out += spike(S) @ V : wave w computes cols e = w*16 .. w*16+15
        #pragma unroll
        for (int ks = 0; ks < 4; ++ks) {
            short8 bV = *(const short8*)&Vs[(w * 16 + l16) * 136 + ks * 32 + quad * 8];
            #pragma unroll
            for (int mt = 0; mt < 4; ++mt) {
                short8 aS = *(const short8*)&Sb[(mt * 16 + l16) * 136 + ks * 32 + quad * 8];
                of[mt] = __builtin_amdgcn_mfma_f32_16x16x32_bf16(aS, bV, of[mt], 0, 0, 0);
            }
        }
    }

    // epilogue: spike(out * 0.125) -> sout_dup [4096][1024] (both halves)
    #pragma unroll
    for (int mt = 0; mt < 4; ++mt)
        #pragma unroll
        for (int r = 0; r < 4; ++r) {
            size_t orow = (size_t)b * 1024 + n0 + mt * 16 + quad * 4 + r;
            int col = h * 64 + w * 16 + l16;
            short v = f2bf(spikef(of[mt][r] * 0.125f));
            sout[orow * 1024 + col]       = v;
            sout[orow * 1024 + 512 + col] = v;
        }
}

extern "C" void kernel_launch(void* const* d_in, const int* in_sizes, int n_in,
                              void* d_out, int out_size, void* d_ws, size_t ws_size,
                              hipStream_t stream) {
    const float* x     = (const float*)d_in[0];
    const float* Wqkv  = (const float*)d_in[1];
    const float* gamma = (const float*)d_in[2];
    const float* beta  = (const float*)d_in[3];
    const float* Wproj = (const float*)d_in[4];
    const float* bproj = (const float*)d_in[5];
    float* out = (float*)d_out;

    char* w = (char*)d_ws;
    short* xs2    = (short*)(w);                       // 8 MB, reused as sout_dup
    short* Wqkv2  = (short*)(w + 8388608);             // 3 MB
    short* Wproj2 = (short*)(w + 11534336);            // 1 MB
    float* qkv    = (float*)(w + 12582912);            // 25 MB
    short* qp     = (short*)(w + 37748736);            // 4 MB
    short* kp     = (short*)(w + 41943040);            // 4 MB
    short* vt     = (short*)(w + 46137344);            // 4 MB
    float* psum   = (float*)(w + 50331648);
    float* psq    = psum + 64 * 1536;
    float* mean   = psq  + 64 * 1536;
    float* istd   = mean + 1536;

    k_splitw<<<3072, 256, 0, stream>>>(Wqkv, Wqkv2, 1536 * 512, 512);
    k_splitw<<<1024, 256, 0, stream>>>(Wproj, Wproj2, 512 * 512, 512);
    k_spike_dup<<<8192, 256, 0, stream>>>(x, xs2);
    k_gemm_bf16<false><<<dim3(12, 32), 256, 0, stream>>>(xs2, Wqkv2, nullptr, qkv, 4096, 1536, 1024);
    k_bn_partial<<<dim3(6, 64), 256, 0, stream>>>(qkv, psum, psq);
    k_bn_finalize<<<6, 256, 0, stream>>>(psum, psq, mean, istd);
    k_bn_spike<<<4096, 256, 0, stream>>>(qkv, mean, istd, gamma, beta, qp, kp, vt);
    k_attn<<<dim3(16, 8, 4), 256, 0, stream>>>(qp, kp, vt, xs2);
    k_gemm_bf16<true><<<dim3(4, 32), 256, 0, stream>>>(xs2, Wproj2, bproj, out, 4096, 512, 1024);
}

// Round 3
// 168.599 us; speedup vs baseline: 4.7845x; 1.1601x over previous
//
#include <hip/hip_runtime.h>

typedef __attribute__((ext_vector_type(8))) short short8;
typedef __attribute__((ext_vector_type(4))) float f32x4;

#define THRE 4.0f

#define GLOAD_LDS16(g, l) \
    __builtin_amdgcn_global_load_lds((const __attribute__((address_space(1))) void*)(g), \
                                     (__attribute__((address_space(3))) void*)(l), 16, 0, 0)

__device__ __forceinline__ float spikef(float x) {
    return floorf(fminf(fmaxf(x, 0.0f), THRE) + 0.5f);
}
__device__ __forceinline__ short f2bf(float f) {   // truncate; exact for small ints
    return (short)(__builtin_bit_cast(unsigned int, f) >> 16);
}

// ---------- fused prep: spike(x)->bf16 dup halves; split W into bf16 hi|lo ----------
__device__ __forceinline__ void splitw1(const float* W, short* Wd, int j, int K) {
    int r = j / K, c = j % K;
    float f = W[j];
    unsigned u = __builtin_bit_cast(unsigned int, f);
    short hi = (short)(u >> 16);
    float fhi = __builtin_bit_cast(float, u & 0xffff0000u);
    Wd[(size_t)r * 2 * K + c]     = hi;
    Wd[(size_t)r * 2 * K + K + c] = f2bf(f - fhi);
}

__global__ void k_prep(const float* __restrict__ x,
                       const float* __restrict__ Wq, const float* __restrict__ Wp,
                       short* __restrict__ xs2, short* __restrict__ Wqd, short* __restrict__ Wpd) {
    int i = blockIdx.x * 256 + threadIdx.x;             // 12288 blocks
    if (i < 2097152) {                                   // x: 4096*512
        int r = i >> 9, c = i & 511;
        short b = f2bf(spikef(x[i]));
        xs2[(size_t)r * 1024 + c]       = b;
        xs2[(size_t)r * 1024 + 512 + c] = b;
    } else if (i < 2883584) {                            // Wqkv: 1536*512
        splitw1(Wq, Wqd, i - 2097152, 512);
    } else {                                             // Wproj: 512*512
        splitw1(Wp, Wpd, i - 2883584, 512);
    }
}

// ---------- bf16 MFMA GEMM, m97-style global_load_lds staging ----------
// C[M,N] = A[M,K] @ B[N,K]^T (+bias). BM = MT*32, BN=128, BK=32, 256 threads.
// Optional fused BN column partial stats (sum, sumsq) per 128-row block stripe.
template<bool BIAS, bool BNSTATS, int MT>
__global__ __launch_bounds__(256) void k_gemm_bf16(const short* __restrict__ A,
                                                   const short* __restrict__ B,
                                                   const float* __restrict__ bias,
                                                   float* __restrict__ C,
                                                   float* __restrict__ psum,
                                                   float* __restrict__ psq,
                                                   int M, int N, int K) {
    constexpr int BM = MT * 32;
    __shared__ short As[BM * 32];    // unpadded: whole-wave frag reads are contiguous
    __shared__ short Bs[128 * 32];
    const int tid  = threadIdx.x;
    const int lane = tid & 63, wv = tid >> 6;
    const int wy = wv >> 1, wx = wv & 1;
    const int quad = lane >> 4, l16 = lane & 15;
    const int m0 = blockIdx.y * BM, n0 = blockIdx.x * 128;

    f32x4 acc[MT][4];
    #pragma unroll
    for (int i = 0; i < MT; ++i)
        #pragma unroll
        for (int j = 0; j < 4; ++j)
            #pragma unroll
            for (int r = 0; r < 4; ++r) acc[i][j][r] = 0.f;

    // staging: chunk c (16B) of tile = row*4 + j ; LDS dest = wave base + lane*16
    const short* gA[BM / 64];
    short* lA[BM / 64];
    #pragma unroll
    for (int b = 0; b < BM / 64; ++b) {
        int c = (b * 4 + wv) * 64 + lane;
        gA[b] = A + (size_t)(m0 + (c >> 2)) * K + (c & 3) * 8;
        lA[b] = &As[(b * 4 + wv) * 512];
    }
    const short* gB[2];
    short* lB[2];
    #pragma unroll
    for (int b = 0; b < 2; ++b) {
        int c = (b * 4 + wv) * 64 + lane;
        gB[b] = B + (size_t)(n0 + (c >> 2)) * K + (c & 3) * 8;
        lB[b] = &Bs[(b * 4 + wv) * 512];
    }

    for (int k0 = 0; k0 < K; k0 += 32) {
        __syncthreads();
        #pragma unroll
        for (int b = 0; b < BM / 64; ++b) GLOAD_LDS16(gA[b] + k0, lA[b]);
        #pragma unroll
        for (int b = 0; b < 2; ++b) GLOAD_LDS16(gB[b] + k0, lB[b]);
        __syncthreads();
        short8 aF[MT], bF[4];
        #pragma unroll
        for (int mt = 0; mt < MT; ++mt)
            aF[mt] = *(const short8*)&As[(wy * MT * 16 + mt * 16 + l16) * 32 + quad * 8];
        #pragma unroll
        for (int nt = 0; nt < 4; ++nt)
            bF[nt] = *(const short8*)&Bs[(wx * 64 + nt * 16 + l16) * 32 + quad * 8];
        #pragma unroll
        for (int mt = 0; mt < MT; ++mt)
            #pragma unroll
            for (int nt = 0; nt < 4; ++nt)
                acc[mt][nt] = __builtin_amdgcn_mfma_f32_16x16x32_bf16(aF[mt], bF[nt], acc[mt][nt], 0, 0, 0);
    }

    float bs[4];
    #pragma unroll
    for (int nt = 0; nt < 4; ++nt) bs[nt] = BIAS ? bias[n0 + wx * 64 + nt * 16 + l16] : 0.f;
    #pragma unroll
    for (int mt = 0; mt < MT; ++mt)
        #pragma unroll
        for (int r = 0; r < 4; ++r) {
            int row = m0 + wy * MT * 16 + mt * 16 + quad * 4 + r;
            float* Cr = C + (size_t)row * N + n0 + wx * 64 + l16;
            #pragma unroll
            for (int nt = 0; nt < 4; ++nt) Cr[nt * 16] = acc[mt][nt][r] + bs[nt];
        }

    if (BNSTATS) {
        // per-block column sums over the BM=128 rows (deterministic order)
        __syncthreads();
        float* PS = (float*)As;   // [8][128]
        float* PQ = (float*)Bs;
        #pragma unroll
        for (int nt = 0; nt < 4; ++nt) {
            float s = 0.f, q = 0.f;
            #pragma unroll
            for (int mt = 0; mt < MT; ++mt)
                #pragma unroll
                for (int r = 0; r < 4; ++r) {
                    float v = acc[mt][nt][r];
                    s += v;
                    q = fmaf(v, v, q);
                }
            PS[(wy * 4 + quad) * 128 + wx * 64 + nt * 16 + l16] = s;
            PQ[(wy * 4 + quad) * 128 + wx * 64 + nt * 16 + l16] = q;
        }
        __syncthreads();
        if (tid < 128) {
            float s = 0.f, q = 0.f;
            #pragma unroll
            for (int i = 0; i < 8; ++i) { s += PS[i * 128 + tid]; q += PQ[i * 128 + tid]; }
            psum[blockIdx.y * 1536 + n0 + tid] = s;
            psq [blockIdx.y * 1536 + n0 + tid] = q;
        }
    }
}

// ---------- BN finalize (sum over 32 row-stripes) ----------
__global__ void k_bn_finalize(const float* __restrict__ psum, const float* __restrict__ psq,
                              float* __restrict__ mean, float* __restrict__ invstd) {
    const int c = blockIdx.x * 256 + threadIdx.x;
    double s = 0.0, q = 0.0;
    for (int b = 0; b < 32; ++b) { s += (double)psum[b * 1536 + c]; q += (double)psq[b * 1536 + c]; }
    const double mu  = s / 4096.0;
    const double var = q / 4096.0 - mu * mu;
    mean[c]   = (float)mu;
    invstd[c] = (float)(1.0 / sqrt(var + 1e-5));
}

// ---------- BN + spike -> packed bf16 q/k (per-head rows) and v (transposed) ----------
__global__ void k_bn_spike(const float* __restrict__ qkv,
                           const float* __restrict__ mean, const float* __restrict__ invstd,
                           const float* __restrict__ gamma, const float* __restrict__ beta,
                           short* __restrict__ qp, short* __restrict__ kp, short* __restrict__ vt) {
    const int row = blockIdx.x;              // 0..4095
    const int b = row >> 10, n = row & 1023;
    const size_t off = (size_t)row * 1536;
    for (int c = threadIdx.x; c < 1536; c += 256) {
        float v = (qkv[off + c] - mean[c]) * invstd[c] * gamma[c] + beta[c];
        short s = f2bf(spikef(v));
        if (c < 512) {
            qp[(((size_t)b * 8 + (c >> 6)) * 1024 + n) * 64 + (c & 63)] = s;
        } else if (c < 1024) {
            int c2 = c - 512;
            kp[(((size_t)b * 8 + (c2 >> 6)) * 1024 + n) * 64 + (c2 & 63)] = s;
        } else {
            int c2 = c - 1024;
            vt[(((size_t)b * 8 + (c2 >> 6)) * 64 + (c2 & 63)) * 1024 + n] = s;
        }
    }
}

// ---------- fused MFMA attention: sout = spike(0.125 * spike(q k^T) v) ----------
// grid (16, 8, 4): 64 q-rows per block, kv tiled by 128. 256 threads = 4 waves.
// All values {0..4}: bit-exact in bf16 MFMA with fp32 accumulate.
__global__ __launch_bounds__(256) void k_attn(const short* __restrict__ qp,
                                              const short* __restrict__ kp,
                                              const short* __restrict__ vt,
                                              short* __restrict__ sout) {
    __shared__ short Qs[64 * 72];    // [qrow][e], pad 64->72
    __shared__ short Ks[128 * 72];   // [kvrow][e], pad
    __shared__ short Vs[64 * 136];   // [e][kvrow], pad 128->136
    __shared__ short Sb[64 * 136];   // spiked S, [qrow][kvrow], pad
    const int tid  = threadIdx.x;
    const int lane = tid & 63, w = tid >> 6;
    const int quad = lane >> 4, l16 = lane & 15;
    const int b = blockIdx.z, h = blockIdx.y;
    const int n0 = blockIdx.x * 64;
    const size_t bh = (size_t)b * 8 + h;

    {
        const int row = tid >> 2, c0 = (tid & 3) * 2;
        const short* g = qp + (bh * 1024 + n0 + row) * 64 + c0 * 8;
        *(short8*)&Qs[row * 72 + c0 * 8]     = *(const short8*)(g);
        *(short8*)&Qs[row * 72 + c0 * 8 + 8] = *(const short8*)(g + 8);
    }
    __syncthreads();
    short8 qf[4][2];
    #pragma unroll
    for (int mt = 0; mt < 4; ++mt)
        #pragma unroll
        for (int kq = 0; kq < 2; ++kq)
            qf[mt][kq] = *(const short8*)&Qs[(mt * 16 + l16) * 72 + kq * 32 + quad * 8];

    f32x4 of[4];
    #pragma unroll
    for (int mt = 0; mt < 4; ++mt)
        #pragma unroll
        for (int r = 0; r < 4; ++r) of[mt][r] = 0.f;

    const int krow = tid >> 1, kc0 = (tid & 1) * 4;
    const int ve = tid >> 2,  vc0 = (tid & 3) * 4;

    for (int j0 = 0; j0 < 1024; j0 += 128) {
        __syncthreads();
        {
            const short* g = kp + (bh * 1024 + j0 + krow) * 64 + kc0 * 8;
            #pragma unroll
            for (int i = 0; i < 4; ++i)
                *(short8*)&Ks[krow * 72 + (kc0 + i) * 8] = *(const short8*)(g + i * 8);
            const short* gv = vt + (bh * 64 + ve) * 1024 + j0 + vc0 * 8;
            #pragma unroll
            for (int i = 0; i < 4; ++i)
                *(short8*)&Vs[ve * 136 + (vc0 + i) * 8] = *(const short8*)(gv + i * 8);
        }
        __syncthreads();

        f32x4 sacc[4][2];
        #pragma unroll
        for (int mt = 0; mt < 4; ++mt)
            #pragma unroll
            for (int nt = 0; nt < 2; ++nt)
                #pragma unroll
                for (int r = 0; r < 4; ++r) sacc[mt][nt][r] = 0.f;
        #pragma unroll
        for (int kq = 0; kq < 2; ++kq) {
            short8 kf0 = *(const short8*)&Ks[(w * 32 +      l16) * 72 + kq * 32 + quad * 8];
            short8 kf1 = *(const short8*)&Ks[(w * 32 + 16 + l16) * 72 + kq * 32 + quad * 8];
            #pragma unroll
            for (int mt = 0; mt < 4; ++mt) {
                sacc[mt][0] = __builtin_amdgcn_mfma_f32_16x16x32_bf16(qf[mt][kq], kf0, sacc[mt][0], 0, 0, 0);
                sacc[mt][1] = __builtin_amdgcn_mfma_f32_16x16x32_bf16(qf[mt][kq], kf1, sacc[mt][1], 0, 0, 0);
            }
        }
        #pragma unroll
        for (int mt = 0; mt < 4; ++mt)
            #pragma unroll
            for (int nt = 0; nt < 2; ++nt)
                #pragma unroll
                for (int r = 0; r < 4; ++r)
                    Sb[(mt * 16 + quad * 4 + r) * 136 + w * 32 + nt * 16 + l16] =
                        f2bf(spikef(sacc[mt][nt][r]));
        __syncthreads();

        #pragma unroll
        for (int ks = 0; ks < 4; ++ks) {
            short8 bV = *(const short8*)&Vs[(w * 16 + l16) * 136 + ks * 32 + quad * 8];
            #pragma unroll
            for (int mt = 0; mt < 4; ++mt) {
                short8 aS = *(const short8*)&Sb[(mt * 16 + l16) * 136 + ks * 32 + quad * 8];
                of[mt] = __builtin_amdgcn_mfma_f32_16x16x32_bf16(aS, bV, of[mt], 0, 0, 0);
            }
        }
    }

    #pragma unroll
    for (int mt = 0; mt < 4; ++mt)
        #pragma unroll
        for (int r = 0; r < 4; ++r) {
            size_t orow = (size_t)b * 1024 + n0 + mt * 16 + quad * 4 + r;
            int col = h * 64 + w * 16 + l16;
            short v = f2bf(spikef(of[mt][r] * 0.125f));
            sout[orow * 1024 + col]       = v;
            sout[orow * 1024 + 512 + col] = v;
        }
}

extern "C" void kernel_launch(void* const* d_in, const int* in_sizes, int n_in,
                              void* d_out, int out_size, void* d_ws, size_t ws_size,
                              hipStream_t stream) {
    const float* x     = (const float*)d_in[0];
    const float* Wqkv  = (const float*)d_in[1];
    const float* gamma = (const float*)d_in[2];
    const float* beta  = (const float*)d_in[3];
    const float* Wproj = (const float*)d_in[4];
    const float* bproj = (const float*)d_in[5];
    float* out = (float*)d_out;

    char* w = (char*)d_ws;
    short* xs2    = (short*)(w);                       // 8 MB, reused as sout_dup
    short* Wqkv2  = (short*)(w + 8388608);             // 3 MB
    short* Wproj2 = (short*)(w + 11534336);            // 1 MB
    float* qkv    = (float*)(w + 12582912);            // 25 MB
    short* qp     = (short*)(w + 37748736);            // 4 MB
    short* kp     = (short*)(w + 41943040);            // 4 MB
    short* vt     = (short*)(w + 46137344);            // 4 MB
    float* psum   = (float*)(w + 50331648);            // 32*1536 floats
    float* psq    = psum + 32 * 1536;
    float* mean   = psq  + 32 * 1536;
    float* istd   = mean + 1536;

    k_prep<<<12288, 256, 0, stream>>>(x, Wqkv, Wproj, xs2, Wqkv2, Wproj2);
    k_gemm_bf16<false, true, 4><<<dim3(12, 32), 256, 0, stream>>>(
        xs2, Wqkv2, nullptr, qkv, psum, psq, 4096, 1536, 1024);
    k_bn_finalize<<<6, 256, 0, stream>>>(psum, psq, mean, istd);
    k_bn_spike<<<4096, 256, 0, stream>>>(qkv, mean, istd, gamma, beta, qp, kp, vt);
    k_attn<<<dim3(16, 8, 4), 256, 0, stream>>>(qp, kp, vt, xs2);
    k_gemm_bf16<true, false, 2><<<dim3(4, 64), 256, 0, stream>>>(
        xs2, Wproj2, bproj, out, nullptr, nullptr, 4096, 512, 1024);
}

// Round 4
// 158.731 us; speedup vs baseline: 5.0820x; 1.0622x over previous
//
#include <hip/hip_runtime.h>

typedef __attribute__((ext_vector_type(8))) short short8;
typedef __attribute__((ext_vector_type(4))) short short4v;
typedef __attribute__((ext_vector_type(4))) float f32x4;

#define THRE 4.0f

#define GLOAD_LDS16(g, l) \
    __builtin_amdgcn_global_load_lds((const __attribute__((address_space(1))) void*)(g), \
                                     (__attribute__((address_space(3))) void*)(l), 16, 0, 0)

__device__ __forceinline__ float spikef(float x) {
    return floorf(fminf(fmaxf(x, 0.0f), THRE) + 0.5f);
}
__device__ __forceinline__ short f2bf(float f) {   // truncate; exact for small ints
    return (short)(__builtin_bit_cast(unsigned int, f) >> 16);
}

// ---------- fused prep: spike(x)->bf16 dup halves; Wqkv -> bf16 hi|lo; Wproj -> hi ----------
__global__ void k_prep(const float* __restrict__ x,
                       const float* __restrict__ Wq, const float* __restrict__ Wp,
                       short* __restrict__ xs2, short* __restrict__ Wqd, short* __restrict__ Wpd) {
    int i = blockIdx.x * 256 + threadIdx.x;             // 12288 blocks
    if (i < 2097152) {                                   // x: 4096*512
        int r = i >> 9, c = i & 511;
        short b = f2bf(spikef(x[i]));
        xs2[(size_t)r * 1024 + c]       = b;
        xs2[(size_t)r * 1024 + 512 + c] = b;
    } else if (i < 2883584) {                            // Wqkv: 1536*512, hi|lo [r][2K]
        int j = i - 2097152;
        int r = j >> 9, c = j & 511;
        float f = Wq[j];
        unsigned u = __builtin_bit_cast(unsigned int, f);
        float fhi = __builtin_bit_cast(float, u & 0xffff0000u);
        Wqd[(size_t)r * 1024 + c]       = (short)(u >> 16);
        Wqd[(size_t)r * 1024 + 512 + c] = f2bf(f - fhi);
    } else {                                             // Wproj: 512*512, hi only
        int j = i - 2883584;
        Wpd[j] = (short)(__builtin_bit_cast(unsigned int, Wp[j]) >> 16);
    }
}

// ---------- bf16 MFMA GEMM, global_load_lds staging ----------
// C[M,N] = A[M,K] @ B[N,K]^T (+bias). BM=MT*32, BN=NT*32, BK=32, 256 threads.
template<bool BIAS, bool BNSTATS, int MT, int NT>
__global__ __launch_bounds__(256) void k_gemm_bf16(const short* __restrict__ A,
                                                   const short* __restrict__ B,
                                                   const float* __restrict__ bias,
                                                   float* __restrict__ C,
                                                   float* __restrict__ psum,
                                                   float* __restrict__ psq,
                                                   int M, int N, int K) {
    constexpr int BM = MT * 32, BN = NT * 32;
    __shared__ short As[BM * 32];    // unpadded: whole-wave frag reads are contiguous
    __shared__ short Bs[BN * 32];
    const int tid  = threadIdx.x;
    const int lane = tid & 63, wv = tid >> 6;
    const int wy = wv >> 1, wx = wv & 1;
    const int quad = lane >> 4, l16 = lane & 15;
    const int m0 = blockIdx.y * BM, n0 = blockIdx.x * BN;

    f32x4 acc[MT][NT];
    #pragma unroll
    for (int i = 0; i < MT; ++i)
        #pragma unroll
        for (int j = 0; j < NT; ++j)
            #pragma unroll
            for (int r = 0; r < 4; ++r) acc[i][j][r] = 0.f;

    // staging: 16B chunk c of tile -> row c>>2, col-chunk c&3; wave-load L covers chunks [L*64, L*64+64)
    constexpr int LA = 2 * MT, LB = 2 * NT;
    const short* gA[(LA + 3) / 4]; short* lA[(LA + 3) / 4]; int nA = 0;
    #pragma unroll
    for (int L0 = 0; L0 < LA; L0 += 4) {
        int L = L0 + wv;
        if (L < LA) {
            int c = L * 64 + lane;
            gA[nA] = A + (size_t)(m0 + (c >> 2)) * K + (c & 3) * 8;
            lA[nA] = &As[L * 512];
            ++nA;
        }
    }
    const short* gB[(LB + 3) / 4]; short* lB[(LB + 3) / 4]; int nB = 0;
    #pragma unroll
    for (int L0 = 0; L0 < LB; L0 += 4) {
        int L = L0 + wv;
        if (L < LB) {
            int c = L * 64 + lane;
            gB[nB] = B + (size_t)(n0 + (c >> 2)) * K + (c & 3) * 8;
            lB[nB] = &Bs[L * 512];
            ++nB;
        }
    }

    for (int k0 = 0; k0 < K; k0 += 32) {
        __syncthreads();
        for (int i = 0; i < nA; ++i) GLOAD_LDS16(gA[i] + k0, lA[i]);
        for (int i = 0; i < nB; ++i) GLOAD_LDS16(gB[i] + k0, lB[i]);
        __syncthreads();
        short8 aF[MT], bF[NT];
        #pragma unroll
        for (int mt = 0; mt < MT; ++mt)
            aF[mt] = *(const short8*)&As[(wy * MT * 16 + mt * 16 + l16) * 32 + quad * 8];
        #pragma unroll
        for (int nt = 0; nt < NT; ++nt)
            bF[nt] = *(const short8*)&Bs[(wx * NT * 16 + nt * 16 + l16) * 32 + quad * 8];
        #pragma unroll
        for (int mt = 0; mt < MT; ++mt)
            #pragma unroll
            for (int nt = 0; nt < NT; ++nt)
                acc[mt][nt] = __builtin_amdgcn_mfma_f32_16x16x32_bf16(aF[mt], bF[nt], acc[mt][nt], 0, 0, 0);
    }

    float bs[NT];
    #pragma unroll
    for (int nt = 0; nt < NT; ++nt) bs[nt] = BIAS ? bias[n0 + wx * NT * 16 + nt * 16 + l16] : 0.f;
    #pragma unroll
    for (int mt = 0; mt < MT; ++mt)
        #pragma unroll
        for (int r = 0; r < 4; ++r) {
            int row = m0 + wy * MT * 16 + mt * 16 + quad * 4 + r;
            float* Cr = C + (size_t)row * N + n0 + wx * NT * 16 + l16;
            #pragma unroll
            for (int nt = 0; nt < NT; ++nt) Cr[nt * 16] = acc[mt][nt][r] + bs[nt];
        }

    if (BNSTATS) {
        __syncthreads();
        float* PS = (float*)As;   // [8][BN]
        float* PQ = (float*)Bs;
        #pragma unroll
        for (int nt = 0; nt < NT; ++nt) {
            float s = 0.f, q = 0.f;
            #pragma unroll
            for (int mt = 0; mt < MT; ++mt)
                #pragma unroll
                for (int r = 0; r < 4; ++r) {
                    float v = acc[mt][nt][r];
                    s += v;
                    q = fmaf(v, v, q);
                }
            PS[(wy * 4 + quad) * BN + wx * NT * 16 + nt * 16 + l16] = s;
            PQ[(wy * 4 + quad) * BN + wx * NT * 16 + nt * 16 + l16] = q;
        }
        __syncthreads();
        if (tid < BN) {
            float s = 0.f, q = 0.f;
            #pragma unroll
            for (int i = 0; i < 8; ++i) { s += PS[i * BN + tid]; q += PQ[i * BN + tid]; }
            psum[blockIdx.y * 1536 + n0 + tid] = s;
            psq [blockIdx.y * 1536 + n0 + tid] = q;
        }
    }
}

// ---------- BN finalize (sum over 32 row-stripes) ----------
__global__ void k_bn_finalize(const float* __restrict__ psum, const float* __restrict__ psq,
                              float* __restrict__ mean, float* __restrict__ invstd) {
    const int c = blockIdx.x * 256 + threadIdx.x;
    double s = 0.0, q = 0.0;
    for (int b = 0; b < 32; ++b) { s += (double)psum[b * 1536 + c]; q += (double)psq[b * 1536 + c]; }
    const double mu  = s / 4096.0;
    const double var = q / 4096.0 - mu * mu;
    mean[c]   = (float)mu;
    invstd[c] = (float)(1.0 / sqrt(var + 1e-5));
}

// ---------- BN + spike -> packed bf16 q/k (per-head) and v (transposed via LDS) ----------
// grid 256 blocks x 16 rows. qp,kp: [B,H,1024,64]; vt: [B,H,64,1024]
__global__ __launch_bounds__(256) void k_bn_spike(const float* __restrict__ qkv,
                           const float* __restrict__ mean, const float* __restrict__ invstd,
                           const float* __restrict__ gamma, const float* __restrict__ beta,
                           short* __restrict__ qp, short* __restrict__ kp, short* __restrict__ vt) {
    __shared__ float sa[1536], sb[1536];   // scale = istd*gamma, shift = beta - mean*scale
    __shared__ short tile[64 * 20];        // v^T tile [e][i], pad 16->20
    const int tid = threadIdx.x;
    const int r0 = blockIdx.x * 16;
    const int b = r0 >> 10, n0 = r0 & 1023;
    for (int c = tid; c < 1536; c += 256) {
        float a = invstd[c] * gamma[c];
        sa[c] = a;
        sb[c] = fmaf(-mean[c], a, beta[c]);
    }
    __syncthreads();

    // q/k: 16 rows x 1024 cols, float4 per item
    for (int t = tid; t < 4096; t += 256) {
        const int i = t >> 8, c = (t & 255) * 4;
        const float4 v = *(const float4*)&qkv[(size_t)(r0 + i) * 1536 + c];
        short4v o;
        o.x = f2bf(spikef(fmaf(v.x, sa[c],     sb[c])));
        o.y = f2bf(spikef(fmaf(v.y, sa[c + 1], sb[c + 1])));
        o.z = f2bf(spikef(fmaf(v.z, sa[c + 2], sb[c + 2])));
        o.w = f2bf(spikef(fmaf(v.w, sa[c + 3], sb[c + 3])));
        const int d = c & 511, h = d >> 6, e = d & 63;
        short* dst = (c < 512 ? qp : kp) + (((size_t)b * 8 + h) * 1024 + r0 - (b << 10) + i) * 64 + e;
        *(short4v*)dst = o;
    }

    // v: per head, transpose through LDS
    const int li = tid >> 4, le0 = (tid & 15) * 4;        // load: row li, cols le0..le0+3
    const int we = tid >> 2, wi0 = (tid & 3) * 4;         // store: e-row we, i-seg wi0
    for (int h = 0; h < 8; ++h) {
        __syncthreads();
        const int c = 1024 + h * 64 + le0;
        const float4 v = *(const float4*)&qkv[(size_t)(r0 + li) * 1536 + c];
        tile[(le0 + 0) * 20 + li] = f2bf(spikef(fmaf(v.x, sa[c],     sb[c])));
        tile[(le0 + 1) * 20 + li] = f2bf(spikef(fmaf(v.y, sa[c + 1], sb[c + 1])));
        tile[(le0 + 2) * 20 + li] = f2bf(spikef(fmaf(v.z, sa[c + 2], sb[c + 2])));
        tile[(le0 + 3) * 20 + li] = f2bf(spikef(fmaf(v.w, sa[c + 3], sb[c + 3])));
        __syncthreads();
        short4v o = *(const short4v*)&tile[we * 20 + wi0];
        *(short4v*)&vt[(((size_t)b * 8 + h) * 64 + we) * 1024 + n0 + wi0] = o;
    }
}

// ---------- fused MFMA attention: sout = spike(0.125 * spike(q k^T) v) ----------
// grid (16, 8, 4): 64 q-rows per block, kv tiled by 128. 256 threads = 4 waves.
// All values {0..4}: bit-exact in bf16 MFMA with fp32 accumulate.
__global__ __launch_bounds__(256) void k_attn(const short* __restrict__ qp,
                                              const short* __restrict__ kp,
                                              const short* __restrict__ vt,
                                              short* __restrict__ sout) {
    __shared__ short Qs[64 * 72];    // [qrow][e], pad 64->72
    __shared__ short Ks[128 * 72];   // [kvrow][e], pad
    __shared__ short Vs[64 * 136];   // [e][kvrow], pad 128->136
    __shared__ short Sb[64 * 136];   // spiked S, [qrow][kvrow], pad
    const int tid  = threadIdx.x;
    const int lane = tid & 63, w = tid >> 6;
    const int quad = lane >> 4, l16 = lane & 15;
    const int b = blockIdx.z, h = blockIdx.y;
    const int n0 = blockIdx.x * 64;
    const size_t bh = (size_t)b * 8 + h;

    {
        const int row = tid >> 2, c0 = (tid & 3) * 2;
        const short* g = qp + (bh * 1024 + n0 + row) * 64 + c0 * 8;
        *(short8*)&Qs[row * 72 + c0 * 8]     = *(const short8*)(g);
        *(short8*)&Qs[row * 72 + c0 * 8 + 8] = *(const short8*)(g + 8);
    }
    __syncthreads();
    short8 qf[4][2];
    #pragma unroll
    for (int mt = 0; mt < 4; ++mt)
        #pragma unroll
        for (int kq = 0; kq < 2; ++kq)
            qf[mt][kq] = *(const short8*)&Qs[(mt * 16 + l16) * 72 + kq * 32 + quad * 8];

    f32x4 of[4];
    #pragma unroll
    for (int mt = 0; mt < 4; ++mt)
        #pragma unroll
        for (int r = 0; r < 4; ++r) of[mt][r] = 0.f;

    const int krow = tid >> 1, kc0 = (tid & 1) * 4;
    const int ve = tid >> 2,  vc0 = (tid & 3) * 4;

    for (int j0 = 0; j0 < 1024; j0 += 128) {
        __syncthreads();
        {
            const short* g = kp + (bh * 1024 + j0 + krow) * 64 + kc0 * 8;
            #pragma unroll
            for (int i = 0; i < 4; ++i)
                *(short8*)&Ks[krow * 72 + (kc0 + i) * 8] = *(const short8*)(g + i * 8);
            const short* gv = vt + (bh * 64 + ve) * 1024 + j0 + vc0 * 8;
            #pragma unroll
            for (int i = 0; i < 4; ++i)
                *(short8*)&Vs[ve * 136 + (vc0 + i) * 8] = *(const short8*)(gv + i * 8);
        }
        __syncthreads();

        f32x4 sacc[4][2];
        #pragma unroll
        for (int mt = 0; mt < 4; ++mt)
            #pragma unroll
            for (int nt = 0; nt < 2; ++nt)
                #pragma unroll
                for (int r = 0; r < 4; ++r) sacc[mt][nt][r] = 0.f;
        #pragma unroll
        for (int kq = 0; kq < 2; ++kq) {
            short8 kf0 = *(const short8*)&Ks[(w * 32 +      l16) * 72 + kq * 32 + quad * 8];
            short8 kf1 = *(const short8*)&Ks[(w * 32 + 16 + l16) * 72 + kq * 32 + quad * 8];
            #pragma unroll
            for (int mt = 0; mt < 4; ++mt) {
                sacc[mt][0] = __builtin_amdgcn_mfma_f32_16x16x32_bf16(qf[mt][kq], kf0, sacc[mt][0], 0, 0, 0);
                sacc[mt][1] = __builtin_amdgcn_mfma_f32_16x16x32_bf16(qf[mt][kq], kf1, sacc[mt][1], 0, 0, 0);
            }
        }
        #pragma unroll
        for (int mt = 0; mt < 4; ++mt)
            #pragma unroll
            for (int nt = 0; nt < 2; ++nt)
                #pragma unroll
                for (int r = 0; r < 4; ++r)
                    Sb[(mt * 16 + quad * 4 + r) * 136 + w * 32 + nt * 16 + l16] =
                        f2bf(spikef(sacc[mt][nt][r]));
        __syncthreads();

        #pragma unroll
        for (int ks = 0; ks < 4; ++ks) {
            short8 bV = *(const short8*)&Vs[(w * 16 + l16) * 136 + ks * 32 + quad * 8];
            #pragma unroll
            for (int mt = 0; mt < 4; ++mt) {
                short8 aS = *(const short8*)&Sb[(mt * 16 + l16) * 136 + ks * 32 + quad * 8];
                of[mt] = __builtin_amdgcn_mfma_f32_16x16x32_bf16(aS, bV, of[mt], 0, 0, 0);
            }
        }
    }

    #pragma unroll
    for (int mt = 0; mt < 4; ++mt)
        #pragma unroll
        for (int r = 0; r < 4; ++r) {
            size_t orow = (size_t)b * 1024 + n0 + mt * 16 + quad * 4 + r;
            sout[orow * 512 + h * 64 + w * 16 + l16] = f2bf(spikef(of[mt][r] * 0.125f));
        }
}

extern "C" void kernel_launch(void* const* d_in, const int* in_sizes, int n_in,
                              void* d_out, int out_size, void* d_ws, size_t ws_size,
                              hipStream_t stream) {
    const float* x     = (const float*)d_in[0];
    const float* Wqkv  = (const float*)d_in[1];
    const float* gamma = (const float*)d_in[2];
    const float* beta  = (const float*)d_in[3];
    const float* Wproj = (const float*)d_in[4];
    const float* bproj = (const float*)d_in[5];
    float* out = (float*)d_out;

    char* w = (char*)d_ws;
    short* xs2    = (short*)(w);                       // 8 MB [4096][1024]; front 4 MB reused as sout [4096][512]
    short* Wqkv2  = (short*)(w + 8388608);             // 3 MB
    short* Wproj2 = (short*)(w + 11534336);            // 0.5 MB
    float* qkv    = (float*)(w + 12582912);            // 24 MB
    short* qp     = (short*)(w + 37748736);            // 4 MB
    short* kp     = (short*)(w + 41943040);            // 4 MB
    short* vt     = (short*)(w + 46137344);            // 4 MB
    float* psum   = (float*)(w + 50331648);            // 32*1536
    float* psq    = psum + 32 * 1536;
    float* mean   = psq  + 32 * 1536;
    float* istd   = mean + 1536;
    short* sout   = xs2;                               // reuse after qkv GEMM is done with xs2

    k_prep<<<12288, 256, 0, stream>>>(x, Wqkv, Wproj, xs2, Wqkv2, Wproj2);
    k_gemm_bf16<false, true, 4, 3><<<dim3(16, 32), 256, 0, stream>>>(
        xs2, Wqkv2, nullptr, qkv, psum, psq, 4096, 1536, 1024);
    k_bn_finalize<<<6, 256, 0, stream>>>(psum, psq, mean, istd);
    k_bn_spike<<<256, 256, 0, stream>>>(qkv, mean, istd, gamma, beta, qp, kp, vt);
    k_attn<<<dim3(16, 8, 4), 256, 0, stream>>>(qp, kp, vt, sout);
    k_gemm_bf16<true, false, 2, 4><<<dim3(4, 64), 256, 0, stream>>>(
        sout, Wproj2, bproj, out, nullptr, nullptr, 4096, 512, 512);
}

// Round 5
// 156.540 us; speedup vs baseline: 5.1531x; 1.0140x over previous
//
#include <hip/hip_runtime.h>

typedef __attribute__((ext_vector_type(8))) short short8;
typedef __attribute__((ext_vector_type(4))) short short4v;
typedef __attribute__((ext_vector_type(4))) float f32x4;
typedef __attribute__((ext_vector_type(2))) unsigned int u32x2;
typedef __attribute__((ext_vector_type(4))) unsigned int u32x4;

#define THRE 4.0f

#define GLOAD_LDS16(g, l) \
    __builtin_amdgcn_global_load_lds((const __attribute__((address_space(1))) void*)(g), \
                                     (__attribute__((address_space(3))) void*)(l), 16, 0, 0)

__device__ __forceinline__ float spikef(float x) {
    return floorf(fminf(fmaxf(x, 0.0f), THRE) + 0.5f);
}
__device__ __forceinline__ unsigned short f2bf(float f) {   // truncate; exact for small ints
    return (unsigned short)(__builtin_bit_cast(unsigned int, f) >> 16);
}

// ---------- fused prep: spike(x)->bf16 dup halves; Wqkv -> bf16 hi|lo; Wproj -> hi ----------
__global__ void k_prep(const float* __restrict__ x,
                       const float* __restrict__ Wq, const float* __restrict__ Wp,
                       short* __restrict__ xs2, short* __restrict__ Wqd, short* __restrict__ Wpd) {
    int i = blockIdx.x * 256 + threadIdx.x;             // 12288 blocks
    if (i < 2097152) {                                   // x: 4096*512
        int r = i >> 9, c = i & 511;
        short b = (short)f2bf(spikef(x[i]));
        xs2[(size_t)r * 1024 + c]       = b;
        xs2[(size_t)r * 1024 + 512 + c] = b;
    } else if (i < 2883584) {                            // Wqkv: 1536*512, hi|lo [r][2K]
        int j = i - 2097152;
        int r = j >> 9, c = j & 511;
        float f = Wq[j];
        unsigned u = __builtin_bit_cast(unsigned int, f);
        float fhi = __builtin_bit_cast(float, u & 0xffff0000u);
        Wqd[(size_t)r * 1024 + c]       = (short)(u >> 16);
        Wqd[(size_t)r * 1024 + 512 + c] = (short)f2bf(f - fhi);
    } else {                                             // Wproj: 512*512, hi only
        int j = i - 2883584;
        Wpd[j] = (short)(__builtin_bit_cast(unsigned int, Wp[j]) >> 16);
    }
}

// ---------- bf16 MFMA GEMM, global_load_lds staging ----------
template<bool BIAS, bool BNSTATS, int MT, int NT>
__global__ __launch_bounds__(256) void k_gemm_bf16(const short* __restrict__ A,
                                                   const short* __restrict__ B,
                                                   const float* __restrict__ bias,
                                                   float* __restrict__ C,
                                                   float* __restrict__ psum,
                                                   float* __restrict__ psq,
                                                   int M, int N, int K) {
    constexpr int BM = MT * 32, BN = NT * 32;
    __shared__ short As[BM * 32];
    __shared__ short Bs[BN * 32];
    const int tid  = threadIdx.x;
    const int lane = tid & 63, wv = tid >> 6;
    const int wy = wv >> 1, wx = wv & 1;
    const int quad = lane >> 4, l16 = lane & 15;
    const int m0 = blockIdx.y * BM, n0 = blockIdx.x * BN;

    f32x4 acc[MT][NT];
    #pragma unroll
    for (int i = 0; i < MT; ++i)
        #pragma unroll
        for (int j = 0; j < NT; ++j)
            #pragma unroll
            for (int r = 0; r < 4; ++r) acc[i][j][r] = 0.f;

    constexpr int LA = 2 * MT, LB = 2 * NT;
    const short* gA[(LA + 3) / 4]; short* lA[(LA + 3) / 4]; int nA = 0;
    #pragma unroll
    for (int L0 = 0; L0 < LA; L0 += 4) {
        int L = L0 + wv;
        if (L < LA) {
            int c = L * 64 + lane;
            gA[nA] = A + (size_t)(m0 + (c >> 2)) * K + (c & 3) * 8;
            lA[nA] = &As[L * 512];
            ++nA;
        }
    }
    const short* gB[(LB + 3) / 4]; short* lB[(LB + 3) / 4]; int nB = 0;
    #pragma unroll
    for (int L0 = 0; L0 < LB; L0 += 4) {
        int L = L0 + wv;
        if (L < LB) {
            int c = L * 64 + lane;
            gB[nB] = B + (size_t)(n0 + (c >> 2)) * K + (c & 3) * 8;
            lB[nB] = &Bs[L * 512];
            ++nB;
        }
    }

    for (int k0 = 0; k0 < K; k0 += 32) {
        __syncthreads();
        for (int i = 0; i < nA; ++i) GLOAD_LDS16(gA[i] + k0, lA[i]);
        for (int i = 0; i < nB; ++i) GLOAD_LDS16(gB[i] + k0, lB[i]);
        __syncthreads();
        short8 aF[MT], bF[NT];
        #pragma unroll
        for (int mt = 0; mt < MT; ++mt)
            aF[mt] = *(const short8*)&As[(wy * MT * 16 + mt * 16 + l16) * 32 + quad * 8];
        #pragma unroll
        for (int nt = 0; nt < NT; ++nt)
            bF[nt] = *(const short8*)&Bs[(wx * NT * 16 + nt * 16 + l16) * 32 + quad * 8];
        #pragma unroll
        for (int mt = 0; mt < MT; ++mt)
            #pragma unroll
            for (int nt = 0; nt < NT; ++nt)
                acc[mt][nt] = __builtin_amdgcn_mfma_f32_16x16x32_bf16(aF[mt], bF[nt], acc[mt][nt], 0, 0, 0);
    }

    float bs[NT];
    #pragma unroll
    for (int nt = 0; nt < NT; ++nt) bs[nt] = BIAS ? bias[n0 + wx * NT * 16 + nt * 16 + l16] : 0.f;
    #pragma unroll
    for (int mt = 0; mt < MT; ++mt)
        #pragma unroll
        for (int r = 0; r < 4; ++r) {
            int row = m0 + wy * MT * 16 + mt * 16 + quad * 4 + r;
            float* Cr = C + (size_t)row * N + n0 + wx * NT * 16 + l16;
            #pragma unroll
            for (int nt = 0; nt < NT; ++nt) Cr[nt * 16] = acc[mt][nt][r] + bs[nt];
        }

    if (BNSTATS) {
        __syncthreads();
        float* PS = (float*)As;
        float* PQ = (float*)Bs;
        #pragma unroll
        for (int nt = 0; nt < NT; ++nt) {
            float s = 0.f, q = 0.f;
            #pragma unroll
            for (int mt = 0; mt < MT; ++mt)
                #pragma unroll
                for (int r = 0; r < 4; ++r) {
                    float v = acc[mt][nt][r];
                    s += v;
                    q = fmaf(v, v, q);
                }
            PS[(wy * 4 + quad) * BN + wx * NT * 16 + nt * 16 + l16] = s;
            PQ[(wy * 4 + quad) * BN + wx * NT * 16 + nt * 16 + l16] = q;
        }
        __syncthreads();
        if (tid < BN) {
            float s = 0.f, q = 0.f;
            #pragma unroll
            for (int i = 0; i < 8; ++i) { s += PS[i * BN + tid]; q += PQ[i * BN + tid]; }
            psum[blockIdx.y * 1536 + n0 + tid] = s;
            psq [blockIdx.y * 1536 + n0 + tid] = q;
        }
    }
}

// ---------- fused BN finalize + spike + pack, channel-sliced ----------
__global__ __launch_bounds__(256) void k_bn_spike(const float* __restrict__ qkv,
                           const float* __restrict__ psum, const float* __restrict__ psq,
                           const float* __restrict__ gamma, const float* __restrict__ beta,
                           short* __restrict__ qp, short* __restrict__ kp, short* __restrict__ vt) {
    __shared__ float sa[64], sb[64];
    __shared__ short tile[64 * 72];
    const int tid = threadIdx.x;
    const int slice = blockIdx.x;            // 0..23
    const int c0 = slice * 64;
    const int r0 = blockIdx.y * 256;
    const int b = r0 >> 10, nb = r0 & 1023;

    if (tid < 64) {
        const int c = c0 + tid;
        double s = 0.0, q = 0.0;
        for (int st = 0; st < 32; ++st) { s += (double)psum[st * 1536 + c]; q += (double)psq[st * 1536 + c]; }
        const double mu  = s / 4096.0;
        const double var = q / 4096.0 - mu * mu;
        const float a = (float)((double)gamma[c] / sqrt(var + 1e-5));
        sa[tid] = a;
        sb[tid] = fmaf(-(float)mu, a, beta[c]);
    }
    __syncthreads();

    const int ch = tid & 63, rq = tid >> 6;
    const float A = sa[ch], Bsh = sb[ch];

    if (slice < 16) {
        const int h = slice & 7;
        short* base = (slice < 8 ? qp : kp) + ((size_t)(b * 8 + h) * 1024 + nb) * 64;
        for (int i = rq; i < 256; i += 4) {
            float v = qkv[(size_t)(r0 + i) * 1536 + c0 + ch];
            base[(size_t)i * 64 + ch] = (short)f2bf(spikef(fmaf(v, A, Bsh)));
        }
    } else {
        const int h = slice - 16;
        const int e = tid >> 2, j0 = (tid & 3) * 16;
        short* vbase = vt + ((size_t)(b * 8 + h) * 64 + e) * 1024 + nb;
        for (int rb = 0; rb < 4; ++rb) {
            __syncthreads();
            for (int i = rq; i < 64; i += 4) {
                float v = qkv[(size_t)(r0 + rb * 64 + i) * 1536 + c0 + ch];
                tile[ch * 72 + i] = (short)f2bf(spikef(fmaf(v, A, Bsh)));
            }
            __syncthreads();
            *(short8*)&vbase[rb * 64 + j0]     = *(const short8*)&tile[e * 72 + j0];
            *(short8*)&vbase[rb * 64 + j0 + 8] = *(const short8*)&tile[e * 72 + j0 + 8];
        }
    }
}

// ---------- fused MFMA attention (S^T trick + per-wave scratch permute + partial PV) ----------
__global__ __launch_bounds__(256) void k_attn(const short* __restrict__ qp,
                                              const short* __restrict__ kp,
                                              const short* __restrict__ vt,
                                              short* __restrict__ sout) {
    __shared__ short SM[26624];              // 53248 B -> 3 blocks/CU (LDS)
    short* Qs = SM;                          // 64*72
    short* Ks = SM + 4608;                   // 128*72
    short* Vs = SM + 13824;                  // 64*136
    unsigned int* SC = (unsigned int*)(SM + 22528);
    const int tid  = threadIdx.x;
    const int lane = tid & 63, w = tid >> 6;
    const int quad = lane >> 4, l16 = lane & 15;
    const int b = blockIdx.z, h = blockIdx.y;
    const int n0 = blockIdx.x * 64;
    const size_t bh = (size_t)b * 8 + h;

    {
        const int row = tid >> 2, c0 = (tid & 3) * 16;
        const short* g = qp + (bh * 1024 + n0 + row) * 64 + c0;
        *(short8*)&Qs[row * 72 + c0]     = *(const short8*)(g);
        *(short8*)&Qs[row * 72 + c0 + 8] = *(const short8*)(g + 8);
    }
    __syncthreads();
    short8 qf[4][2];
    #pragma unroll
    for (int mt = 0; mt < 4; ++mt)
        #pragma unroll
        for (int kq = 0; kq < 2; ++kq)
            qf[mt][kq] = *(const short8*)&Qs[(mt * 16 + l16) * 72 + kq * 32 + quad * 8];

    f32x4 of[4][4];
    #pragma unroll
    for (int et = 0; et < 4; ++et)
        #pragma unroll
        for (int mt = 0; mt < 4; ++mt)
            #pragma unroll
            for (int r = 0; r < 4; ++r) of[et][mt][r] = 0.f;

    const int krow = tid >> 1, kc0 = (tid & 1) * 32;
    const int ve = tid >> 2,  vc0 = (tid & 3) * 32;
    unsigned int* buf0 = SC + w * 256;
    unsigned int* buf1 = SC + 1024 + w * 256;
    const int s0 = (l16 + 16 * ((2 * quad) & 3)) * 4 + (quad >> 1) * 2;
    const int s1 = (l16 + 16 * ((2 * quad + 1) & 3)) * 4 + (quad >> 1) * 2;

    for (int j0 = 0; j0 < 1024; j0 += 128) {
        __syncthreads();
        {
            const short* g = kp + (bh * 1024 + j0 + krow) * 64 + kc0;
            #pragma unroll
            for (int i = 0; i < 4; ++i)
                *(short8*)&Ks[krow * 72 + kc0 + i * 8] = *(const short8*)(g + i * 8);
            const short* gv = vt + (bh * 64 + ve) * 1024 + j0 + vc0;
            #pragma unroll
            for (int i = 0; i < 4; ++i)
                *(short8*)&Vs[ve * 136 + vc0 + i * 8] = *(const short8*)(gv + i * 8);
        }
        __syncthreads();

        f32x4 sacc[4][2];
        #pragma unroll
        for (int mt = 0; mt < 4; ++mt)
            #pragma unroll
            for (int nt = 0; nt < 2; ++nt)
                #pragma unroll
                for (int r = 0; r < 4; ++r) sacc[mt][nt][r] = 0.f;
        #pragma unroll
        for (int kq = 0; kq < 2; ++kq) {
            short8 kf0 = *(const short8*)&Ks[(w * 32 +      l16) * 72 + kq * 32 + quad * 8];
            short8 kf1 = *(const short8*)&Ks[(w * 32 + 16 + l16) * 72 + kq * 32 + quad * 8];
            #pragma unroll
            for (int mt = 0; mt < 4; ++mt) {
                sacc[mt][0] = __builtin_amdgcn_mfma_f32_16x16x32_bf16(kf0, qf[mt][kq], sacc[mt][0], 0, 0, 0);
                sacc[mt][1] = __builtin_amdgcn_mfma_f32_16x16x32_bf16(kf1, qf[mt][kq], sacc[mt][1], 0, 0, 0);
            }
        }
        short8 aS[4];
        #pragma unroll
        for (int mt = 0; mt < 4; ++mt) {
            unsigned int pk[4];
            #pragma unroll
            for (int nt = 0; nt < 2; ++nt)
                #pragma unroll
                for (int rp = 0; rp < 2; ++rp) {
                    unsigned int lo = f2bf(spikef(sacc[mt][nt][2 * rp]));
                    unsigned int hi = f2bf(spikef(sacc[mt][nt][2 * rp + 1]));
                    pk[nt * 2 + rp] = lo | (hi << 16);
                }
            unsigned int* buf = (mt & 1) ? buf1 : buf0;
            u32x2 wa; wa.x = pk[0]; wa.y = pk[1];
            u32x2 wb; wb.x = pk[2]; wb.y = pk[3];
            *(u32x2*)&buf[lane * 4]     = wa;
            *(u32x2*)&buf[lane * 4 + 2] = wb;
            if (mt > 0) {
                unsigned int* pb = (mt & 1) ? buf0 : buf1;
                u32x2 lo = *(const u32x2*)&pb[s0];
                u32x2 hi = *(const u32x2*)&pb[s1];
                u32x4 t; t.x = lo.x; t.y = lo.y; t.z = hi.x; t.w = hi.y;
                aS[mt - 1] = __builtin_bit_cast(short8, t);
            }
        }
        {
            u32x2 lo = *(const u32x2*)&buf1[s0];
            u32x2 hi = *(const u32x2*)&buf1[s1];
            u32x4 t; t.x = lo.x; t.y = lo.y; t.z = hi.x; t.w = hi.y;
            aS[3] = __builtin_bit_cast(short8, t);
        }

        #pragma unroll
        for (int et = 0; et < 4; ++et) {
            short8 bV = *(const short8*)&Vs[(et * 16 + l16) * 136 + w * 32 + quad * 8];
            #pragma unroll
            for (int mt = 0; mt < 4; ++mt)
                of[et][mt] = __builtin_amdgcn_mfma_f32_16x16x32_bf16(aS[mt], bV, of[et][mt], 0, 0, 0);
        }
    }

    __syncthreads();
    float* P2 = (float*)Ks;
    float* P3 = (float*)Vs;
    if (w == 2 || w == 3) {
        float* P = (w == 2) ? P2 : P3;
        #pragma unroll
        for (int et = 0; et < 4; ++et)
            #pragma unroll
            for (int mt = 0; mt < 4; ++mt)
                *(f32x4*)&P[(et * 16 + l16) * 68 + mt * 16 + quad * 4] = of[et][mt];
    }
    __syncthreads();
    if (w == 0 || w == 1) {
        float* P = (w == 0) ? P2 : P3;
        #pragma unroll
        for (int et = 0; et < 4; ++et)
            #pragma unroll
            for (int mt = 0; mt < 4; ++mt) {
                f32x4 t = *(const f32x4*)&P[(et * 16 + l16) * 68 + mt * 16 + quad * 4];
                #pragma unroll
                for (int r = 0; r < 4; ++r) of[et][mt][r] += t[r];
            }
    }
    __syncthreads();
    if (w == 1) {
        #pragma unroll
        for (int et = 0; et < 4; ++et)
            #pragma unroll
            for (int mt = 0; mt < 4; ++mt)
                *(f32x4*)&P2[(et * 16 + l16) * 68 + mt * 16 + quad * 4] = of[et][mt];
    }
    __syncthreads();
    if (w == 0) {
        #pragma unroll
        for (int et = 0; et < 4; ++et)
            #pragma unroll
            for (int mt = 0; mt < 4; ++mt) {
                f32x4 t = *(const f32x4*)&P2[(et * 16 + l16) * 68 + mt * 16 + quad * 4];
                #pragma unroll
                for (int r = 0; r < 4; ++r) {
                    size_t orow = (size_t)b * 1024 + n0 + mt * 16 + quad * 4 + r;
                    sout[orow * 512 + h * 64 + et * 16 + l16] =
                        (short)f2bf(spikef((of[et][mt][r] + t[r]) * 0.125f));
                }
            }
    }
}

extern "C" void kernel_launch(void* const* d_in, const int* in_sizes, int n_in,
                              void* d_out, int out_size, void* d_ws, size_t ws_size,
                              hipStream_t stream) {
    const float* x     = (const float*)d_in[0];
    const float* Wqkv  = (const float*)d_in[1];
    const float* gamma = (const float*)d_in[2];
    const float* beta  = (const float*)d_in[3];
    const float* Wproj = (const float*)d_in[4];
    const float* bproj = (const float*)d_in[5];
    float* out = (float*)d_out;

    char* w = (char*)d_ws;
    short* xs2    = (short*)(w);
    short* Wqkv2  = (short*)(w + 8388608);
    short* Wproj2 = (short*)(w + 11534336);
    float* qkv    = (float*)(w + 12582912);
    short* qp     = (short*)(w + 37748736);
    short* kp     = (short*)(w + 41943040);
    short* vt     = (short*)(w + 46137344);
    float* psum   = (float*)(w + 50331648);
    float* psq    = psum + 32 * 1536;
    short* sout   = xs2;

    k_prep<<<12288, 256, 0, stream>>>(x, Wqkv, Wproj, xs2, Wqkv2, Wproj2);
    k_gemm_bf16<false, true, 4, 3><<<dim3(16, 32), 256, 0, stream>>>(
        xs2, Wqkv2, nullptr, qkv, psum, psq, 4096, 1536, 1024);
    k_bn_spike<<<dim3(24, 16), 256, 0, stream>>>(qkv, psum, psq, gamma, beta, qp, kp, vt);
    k_attn<<<dim3(16, 8, 4), 256, 0, stream>>>(qp, kp, vt, sout);
    k_gemm_bf16<true, false, 1, 4><<<dim3(4, 128), 256, 0, stream>>>(
        sout, Wproj2, bproj, out, nullptr, nullptr, 4096, 512, 512);
}